// Round 10
// baseline (282.450 us; speedup 1.0000x reference)
//
#include <hip/hip_runtime.h>

typedef __bf16 bf16x8 __attribute__((ext_vector_type(8)));
typedef float f32x4 __attribute__((ext_vector_type(4)));
typedef unsigned int u32;

#define ROW_B   304                 // bytes per row within one copy (152 elems)
#define COPY_B  (31 * ROW_B)        // 9424 B per copy
#define NCOPY   4                   // copies shifted by 0,1,2,3 elements

__device__ __forceinline__ unsigned short f2bf(float f) {
    u32 u = __builtin_bit_cast(u32, f);
    return (unsigned short)((u + 0x7FFFu + ((u >> 16) & 1u)) >> 16);  // RNE
}
__device__ __forceinline__ int refl(int i) {  // reflect index into [0,512)
    return i < 0 ? -i : (i > 511 ? 1022 - i : i);
}

// Block (x=half, y=h0/16, z=n): sample n, rows h0..h0+15, cols [256*half,+256)
// as 2 chunks of 128. Wave w owns cols [16w,16w+16) of each 64-col subtile.
// K = 15x15 taps padded to 16x16 = 256 = 8 MFMA K-steps (HW-validated mapping):
// k = 32*ks + 8*g + j  ->  kh = 2*ks + (g>>1), kw = 8*(g&1) + j   (g = lane>>4)
// B-fragment for (ks,t): 8 bf16 at staged elem X..X+7, X = w0*64+wave*16+g1*8+t+1.
// Copy c = X mod 4 holds elem e at byte 2(e-c) -> every fragment is a direct
// aligned LDS read at an immediate offset. Zero VALU in the inner loop.
template <int MODE>
__global__ __launch_bounds__(256, 4) void dynconv(const float* __restrict__ x,
                                                  const float* __restrict__ kern,
                                                  float* __restrict__ out,
                                                  float* __restrict__ partial) {
    __shared__ __align__(16) unsigned short lds4[NCOPY * COPY_B / 2];  // 37696 B
    __shared__ float wm[4];

    const int tid  = threadIdx.x;
    const int lane = tid & 63;
    const int wave = tid >> 6;
    const int half = blockIdx.x;            // 0/1: which 256-col half
    const int h0   = blockIdx.y * 16;
    const int n    = blockIdx.z;
    const int hbase = half * 256;

    const float* xs = x + (size_t)n * (16u * 512u * 512u);

    // ---- A fragments: kernel weights, zero-padded to 16x16 taps ----
    const int oca = lane & 15;
    const int g   = lane >> 4;
    const int g1  = g & 1;
    const int g2  = g >> 1;
    bf16x8 afrag[8];
    {
        const float* kp = kern + ((size_t)n * 16 + oca) * 225;
        #pragma unroll
        for (int ks = 0; ks < 8; ++ks) {
            const int kh = 2 * ks + g2;
            #pragma unroll
            for (int j = 0; j < 8; ++j) {
                const int kwv = 8 * g1 + j;
                float v = 0.f;
                if (kh < 15 && kwv < 15) v = kp[kh * 15 + kwv];
                afrag[ks][j] = (__bf16)v;
            }
        }
    }

    // ---- MODE 1: per-sample max from the 64 partials of sample n ----
    float scale = 0.f;
    if constexpr (MODE == 1) {
        float pv = partial[(n << 6) + lane];
        #pragma unroll
        for (int off = 32; off > 0; off >>= 1) pv = fmaxf(pv, __shfl_xor(pv, off, 64));
        scale = 1.0f / pv;
    }

    const int hh = lane & 15;               // B n-dim: output row offset

    // ---- stage 4 shifted copies of a 31 x 144 tile (cols c0q-8..c0q+135) ----
    // unit (rr, cs): elems 8cs..8cs+10 of row rr; copy c gets elems 8cs+c..+7.
    auto stage = [&](int c0q) {
        for (int u = tid; u < 31 * 18; u += 256) {
            const int rr = u / 18;
            const int cs = u - rr * 18;
            const float* rowp = xs + refl(h0 - 7 + rr) * 512;
            const int gc0 = c0q - 8 + 8 * cs;
            float v[11];
            if (gc0 >= 0 && gc0 <= 501) {           // interior fast path
                const float4 a  = *(const float4*)(rowp + gc0);
                const float4 b4 = *(const float4*)(rowp + gc0 + 4);
                v[0] = a.x;  v[1] = a.y;  v[2] = a.z;  v[3] = a.w;
                v[4] = b4.x; v[5] = b4.y; v[6] = b4.z; v[7] = b4.w;
                v[8] = rowp[gc0 + 8]; v[9] = rowp[gc0 + 9]; v[10] = rowp[gc0 + 10];
            } else {                                // border reflect, scalar
                #pragma unroll
                for (int i = 0; i < 11; ++i) v[i] = rowp[refl(gc0 + i)];
            }
            unsigned short b[11];
            #pragma unroll
            for (int i = 0; i < 11; ++i) b[i] = f2bf(v[i]);
            char* wp = (char*)lds4 + rr * ROW_B + 16 * cs;
            #pragma unroll
            for (int c = 0; c < NCOPY; ++c) {
                uint4 q;
                q.x = (u32)b[c]     | ((u32)b[c + 1] << 16);
                q.y = (u32)b[c + 2] | ((u32)b[c + 3] << 16);
                q.z = (u32)b[c + 4] | ((u32)b[c + 5] << 16);
                q.w = (u32)b[c + 6] | ((u32)b[c + 7] << 16);
                *(uint4*)(wp + c * COPY_B) = q;
            }
        }
    };

    // per-lane LDS base: row (hh+g2), col words for (wave,g1); rest is immediate
    const char* lbase = (const char*)lds4 + (hh + g2) * ROW_B + 32 * wave + 16 * g1;

    // ---- conv of one 16h x 64w subtile (w0 compile-time) ----
    auto conv = [&](auto w0c, f32x4* acc) {
        constexpr int w0 = decltype(w0c)::value;
        #pragma unroll
        for (int t = 0; t < 16; ++t) acc[t] = f32x4{0.f, 0.f, 0.f, 0.f};
        #pragma unroll
        for (int ks = 0; ks < 8; ++ks) {
            #pragma unroll
            for (int t = 0; t < 16; ++t) {
                const int c   = (t + 1) & 3;
                const int sh  = (t + 1) - c;          // multiple of 4
                const int off = c * COPY_B + ks * (2 * ROW_B) + w0 * 128 + 2 * sh;
                uint4 dv;
                if ((sh & 4) == 0) {                  // 16B-aligned: one b128
                    dv = *(const uint4*)(lbase + off);
                } else {                              // 8B-aligned: two b64
                    const uint2 lo = *(const uint2*)(lbase + off);
                    const uint2 hi = *(const uint2*)(lbase + off + 8);
                    dv.x = lo.x; dv.y = lo.y; dv.z = hi.x; dv.w = hi.y;
                }
                acc[t] = __builtin_amdgcn_mfma_f32_16x16x32_bf16(
                    afrag[ks], __builtin_bit_cast(bf16x8, dv), acc[t], 0, 0, 0);
            }
        }
    };

    float m = -3.4e38f;
    #pragma unroll 1
    for (int ch = 0; ch < 2; ++ch) {
        __syncthreads();
        stage(hbase + ch * 128);
        __syncthreads();
        #pragma unroll
        for (int w0 = 0; w0 < 2; ++w0) {
            f32x4 acc[16];
            if (w0 == 0) conv(std::integral_constant<int, 0>{}, acc);
            else         conv(std::integral_constant<int, 1>{}, acc);
            if constexpr (MODE == 0) {
                #pragma unroll
                for (int t = 0; t < 16; ++t)
                    #pragma unroll
                    for (int r = 0; r < 4; ++r) m = fmaxf(m, acc[t][r]);
            } else {
                // direct stores: lane covers w = wave*16 + 4q..4q+3 (64B/lane line)
                #pragma unroll
                for (int r = 0; r < 4; ++r) {
                    const int oc = 4 * g + r;
                    float* rowp = out + (((size_t)(oc * 16 + n)) * 512 + (h0 + hh)) * 512
                                  + hbase + ch * 128 + w0 * 64 + wave * 16;
                    #pragma unroll
                    for (int q = 0; q < 4; ++q) {
                        f32x4 v;
                        v[0] = acc[4 * q + 0][r] * scale;
                        v[1] = acc[4 * q + 1][r] * scale;
                        v[2] = acc[4 * q + 2][r] * scale;
                        v[3] = acc[4 * q + 3][r] * scale;
                        *(f32x4*)(rowp + 4 * q) = v;
                    }
                }
            }
        }
    }

    if constexpr (MODE == 0) {
        #pragma unroll
        for (int off = 32; off > 0; off >>= 1) m = fmaxf(m, __shfl_xor(m, off, 64));
        if (lane == 0) wm[wave] = m;
        __syncthreads();
        if (tid == 0)
            partial[((blockIdx.z * 32 + blockIdx.y) << 1) + blockIdx.x] =
                fmaxf(fmaxf(wm[0], wm[1]), fmaxf(wm[2], wm[3]));
    }
}

extern "C" void kernel_launch(void* const* d_in, const int* in_sizes, int n_in,
                              void* d_out, int out_size, void* d_ws, size_t ws_size,
                              hipStream_t stream) {
    (void)in_sizes; (void)n_in; (void)out_size; (void)ws_size;
    const float* x  = (const float*)d_in[0];
    const float* k  = (const float*)d_in[1];
    float* out      = (float*)d_out;
    float* partial  = (float*)d_ws;          // 1024 floats

    dim3 grid(2, 32, 16);   // (col half, h-tile, sample) = 1024 blocks = 4/CU
    dim3 block(256);
    dynconv<0><<<grid, block, 0, stream>>>(x, k, out, partial);  // max pass
    dynconv<1><<<grid, block, 0, stream>>>(x, k, out, partial);  // scale+store pass
}

// Round 11
// 235.600 us; speedup vs baseline: 1.1989x; 1.1989x over previous
//
#include <hip/hip_runtime.h>

typedef __bf16 bf16x8 __attribute__((ext_vector_type(8)));
typedef float f32x4 __attribute__((ext_vector_type(4)));
typedef unsigned int u32;
typedef unsigned short u16;

#define PDIM 528                      // padded image dim (rows -7.., cols -8..)
#define PIMG (PDIM * PDIM)            // per-sample padded elems
#define IN_STRIDE 56                  // LDS row stride, elems (112 B, b128-aligned)
#define IN_ROWS   31                  // 16 out rows + 14 halo + 1 kh=15 slot

__device__ __forceinline__ u16 f2bf(float f) {
    u32 u = __builtin_bit_cast(u32, f);
    return (u16)((u + 0x7FFFu + ((u >> 16) & 1u)) >> 16);  // RNE
}
__device__ __forceinline__ int refl(int i) {  // reflect into [0,512)
    return i < 0 ? -i : (i > 511 ? 1022 - i : i);
}

// ---------- pre-pass: x[:,0] f32 -> reflect-padded bf16 image P ----------
// P[n][pr][pc] = bf16(x[n,0,refl(pr-7),refl(pc-8)]),  pr,pc in [0,528)
__global__ __launch_bounds__(256) void cvtpad(const float* __restrict__ x,
                                              u16* __restrict__ P) {
    const int u  = blockIdx.x * 256 + threadIdx.x;   // 16*528*66 units exactly
    const int n  = u / (PDIM * 66);
    const int r  = u - n * (PDIM * 66);
    const int pr = r / 66;
    const int cs = r - pr * 66;
    const int pc0 = cs * 8;
    const float* sx = x + (size_t)n * (16u * 512u * 512u) + (size_t)refl(pr - 7) * 512;
    const int g0 = pc0 - 8;
    float v[8];
    if (g0 >= 0 && g0 <= 504) {
        const float4 a = *(const float4*)(sx + g0);
        const float4 b = *(const float4*)(sx + g0 + 4);
        v[0] = a.x; v[1] = a.y; v[2] = a.z; v[3] = a.w;
        v[4] = b.x; v[5] = b.y; v[6] = b.z; v[7] = b.w;
    } else {
        #pragma unroll
        for (int i = 0; i < 8; ++i) v[i] = sx[refl(g0 + i)];
    }
    uint4 q;
    q.x = (u32)f2bf(v[0]) | ((u32)f2bf(v[1]) << 16);
    q.y = (u32)f2bf(v[2]) | ((u32)f2bf(v[3]) << 16);
    q.z = (u32)f2bf(v[4]) | ((u32)f2bf(v[5]) << 16);
    q.w = (u32)f2bf(v[6]) | ((u32)f2bf(v[7]) << 16);
    *(uint4*)(P + (size_t)n * PIMG + (size_t)pr * PDIM + pc0) = q;
}

// ---------- conv passes ----------
// Block (bx,by,bz): sample n=bz, rows h0=by*16..+15, cols c0=bx*32..+31, 16 oc.
// Wave w owns cols [c0+8w, c0+8w+8) via t=0..7; acc[8] f32x4 (32 regs).
// K = 15x15 padded to 16x16 = 8 MFMA K-steps (HW-validated mapping):
// k = 32*ks + 8*g + j -> kh = 2*ks + (g>>1), kw = 8*(g&1) + j   (g = lane>>4)
// B-fragment (ks,t) = staged elems X..X+7, X = 8*wave + 8*g1 + t + 1.
// MODE 0: per-block max -> partial.  MODE 1: reduce partials, scale, store.
template <int MODE>
__global__ __launch_bounds__(256) void dynconv(const u16* __restrict__ P,
                                               const float* __restrict__ kern,
                                               float* __restrict__ out,
                                               float* __restrict__ partial) {
    __shared__ __align__(16) u16 lds_in[IN_ROWS * IN_STRIDE];  // 3472 B
    __shared__ float wm[4];

    const int tid  = threadIdx.x;
    const int lane = tid & 63;
    const int wave = tid >> 6;
    const int c0 = blockIdx.x * 32;
    const int h0 = blockIdx.y * 16;
    const int n  = blockIdx.z;

    // ---- stage: branch-free b128 copy from padded image (single round) ----
    // unit (rr, cs8): 8 elems; staged local col j == padded col c0 + j
    if (tid < IN_ROWS * 6) {
        const int rr  = tid / 6;
        const int cs8 = tid - rr * 6;
        const uint4 q = *(const uint4*)(P + (size_t)n * PIMG
                                        + (size_t)(h0 + rr) * PDIM + c0 + 8 * cs8);
        *(uint4*)&lds_in[rr * IN_STRIDE + 8 * cs8] = q;
    }

    // ---- A fragments: weights, zero-padded to 16x16 taps ----
    const int oca = lane & 15;
    const int g   = lane >> 4;
    const int g1  = g & 1;
    const int g2  = g >> 1;
    bf16x8 afrag[8];
    {
        const float* kp = kern + ((size_t)n * 16 + oca) * 225;
        #pragma unroll
        for (int ks = 0; ks < 8; ++ks) {
            const int kh = 2 * ks + g2;
            #pragma unroll
            for (int j = 0; j < 8; ++j) {
                const int kwv = 8 * g1 + j;
                float v = 0.f;
                if (kh < 15 && kwv < 15) v = kp[kh * 15 + kwv];
                afrag[ks][j] = (__bf16)v;
            }
        }
    }

    // ---- MODE 1: per-sample max from this sample's 512 partials ----
    float scale = 0.f;
    if constexpr (MODE == 1) {
        const float* pp = partial + n * 512 + lane * 8;
        const float4 a = *(const float4*)pp;
        const float4 b = *(const float4*)(pp + 4);
        float pv = fmaxf(fmaxf(fmaxf(a.x, a.y), fmaxf(a.z, a.w)),
                         fmaxf(fmaxf(b.x, b.y), fmaxf(b.z, b.w)));
        #pragma unroll
        for (int off = 32; off > 0; off >>= 1) pv = fmaxf(pv, __shfl_xor(pv, off, 64));
        scale = 1.0f / pv;
    }

    __syncthreads();

    // ---- conv: 8 K-steps, double-buffered E reads (one step ahead) ----
    const int hh = lane & 15;
    const char* lbase = (const char*)lds_in
                        + (hh + g2) * (IN_STRIDE * 2) + 16 * (wave + g1);

    f32x4 acc[8];
    #pragma unroll
    for (int t = 0; t < 8; ++t) acc[t] = f32x4{0.f, 0.f, 0.f, 0.f};

    u32 Ea[8], Eb[8];
#define LDE(E, ks) do {                                                        \
        const uint4 _a = *(const uint4*)(lbase + (ks) * (2 * IN_STRIDE * 2));  \
        const uint4 _b = *(const uint4*)(lbase + (ks) * (2 * IN_STRIDE * 2) + 16); \
        E[0] = _a.x; E[1] = _a.y; E[2] = _a.z; E[3] = _a.w;                    \
        E[4] = _b.x; E[5] = _b.y; E[6] = _b.z; E[7] = _b.w; } while (0)
#define KSTEP(E, ks) do {                                                      \
        _Pragma("unroll")                                                      \
        for (int t = 0; t < 8; ++t) {                                          \
            const int s = t + 1, xb = s >> 1;                                  \
            u32 d0, d1, d2, d3;                                                \
            if (s & 1) {                                                       \
                d0 = __builtin_amdgcn_alignbit(E[xb + 1], E[xb], 16);          \
                d1 = __builtin_amdgcn_alignbit(E[xb + 2], E[xb + 1], 16);      \
                d2 = __builtin_amdgcn_alignbit(E[xb + 3], E[xb + 2], 16);      \
                d3 = __builtin_amdgcn_alignbit(E[xb + 4], E[xb + 3], 16);      \
            } else { d0 = E[xb]; d1 = E[xb + 1]; d2 = E[xb + 2]; d3 = E[xb + 3]; } \
            uint4 dv; dv.x = d0; dv.y = d1; dv.z = d2; dv.w = d3;              \
            acc[t] = __builtin_amdgcn_mfma_f32_16x16x32_bf16(                  \
                afrag[ks], __builtin_bit_cast(bf16x8, dv), acc[t], 0, 0, 0);   \
        } } while (0)

    LDE(Ea, 0);
    LDE(Eb, 1); KSTEP(Ea, 0);
    LDE(Ea, 2); KSTEP(Eb, 1);
    LDE(Eb, 3); KSTEP(Ea, 2);
    LDE(Ea, 4); KSTEP(Eb, 3);
    LDE(Eb, 5); KSTEP(Ea, 4);
    LDE(Ea, 6); KSTEP(Eb, 5);
    LDE(Eb, 7); KSTEP(Ea, 6);
    KSTEP(Eb, 7);
#undef LDE
#undef KSTEP

    if constexpr (MODE == 0) {
        float m = -3.4e38f;
        #pragma unroll
        for (int t = 0; t < 8; ++t)
            #pragma unroll
            for (int r = 0; r < 4; ++r) m = fmaxf(m, acc[t][r]);
        #pragma unroll
        for (int off = 32; off > 0; off >>= 1) m = fmaxf(m, __shfl_xor(m, off, 64));
        if (lane == 0) wm[wave] = m;
        __syncthreads();
        if (tid == 0)
            partial[n * 512 + blockIdx.y * 16 + blockIdx.x] =
                fmaxf(fmaxf(wm[0], wm[1]), fmaxf(wm[2], wm[3]));
    } else {
        // lane stores cols c0+8w..+7 of row h0+hh for oc = 4g+r  (2 x f32x4)
        #pragma unroll
        for (int r = 0; r < 4; ++r) {
            const int oc = 4 * g + r;
            float* rowp = out + (((size_t)(oc * 16 + n)) * 512 + (size_t)(h0 + hh)) * 512
                          + c0 + 8 * wave;
            f32x4 v0, v1;
            v0[0] = acc[0][r] * scale; v0[1] = acc[1][r] * scale;
            v0[2] = acc[2][r] * scale; v0[3] = acc[3][r] * scale;
            v1[0] = acc[4][r] * scale; v1[1] = acc[5][r] * scale;
            v1[2] = acc[6][r] * scale; v1[3] = acc[7][r] * scale;
            *(f32x4*)(rowp)     = v0;
            *(f32x4*)(rowp + 4) = v1;
        }
    }
}

extern "C" void kernel_launch(void* const* d_in, const int* in_sizes, int n_in,
                              void* d_out, int out_size, void* d_ws, size_t ws_size,
                              hipStream_t stream) {
    (void)in_sizes; (void)n_in; (void)out_size; (void)ws_size;
    const float* x  = (const float*)d_in[0];
    const float* k  = (const float*)d_in[1];
    float* out      = (float*)d_out;
    u16* P          = (u16*)d_ws;                              // 8.9 MB padded bf16
    float* partial  = (float*)((char*)d_ws + (16u << 20));     // 8192 floats @ +16MB

    cvtpad<<<dim3(16 * PDIM * 66 / 256), dim3(256), 0, stream>>>(x, P);
    dim3 grid(16, 32, 16);   // 32-col x 16-row x sample = 8192 blocks (~32/CU queued)
    dim3 block(256);
    dynconv<0><<<grid, block, 0, stream>>>(P, k, out, partial);  // max pass
    dynconv<1><<<grid, block, 0, stream>>>(P, k, out, partial);  // scale+store pass
}

// Round 12
// 108.315 us; speedup vs baseline: 2.6077x; 2.1751x over previous
//
#include <hip/hip_runtime.h>

typedef __bf16 bf16x8 __attribute__((ext_vector_type(8)));
typedef float f32x4 __attribute__((ext_vector_type(4)));
typedef unsigned int u32;
typedef unsigned short u16;

#define PDIM 528                      // padded image dim (rows -7.., cols -8..)
#define PIMG (PDIM * PDIM)            // per-sample padded elems
#define IN_STRIDE 56                  // LDS row stride, elems (112 B, b128-aligned)
#define IN_ROWS   31                  // 16 out rows + 14 halo + 1 kh=15 slot

__device__ __forceinline__ u16 f2bf(float f) {
    u32 u = __builtin_bit_cast(u32, f);
    return (u16)((u + 0x7FFFu + ((u >> 16) & 1u)) >> 16);  // RNE
}
__device__ __forceinline__ int refl(int i) {  // reflect into [0,512)
    return i < 0 ? -i : (i > 511 ? 1022 - i : i);
}

// ---------- pre-pass 1: x[:,0] f32 -> reflect-padded bf16 image P ----------
__global__ __launch_bounds__(256) void cvtpad(const float* __restrict__ x,
                                              u16* __restrict__ P) {
    const int u  = blockIdx.x * 256 + threadIdx.x;   // 16*528*66 units exactly
    const int n  = u / (PDIM * 66);
    const int r  = u - n * (PDIM * 66);
    const int pr = r / 66;
    const int cs = r - pr * 66;
    const int pc0 = cs * 8;
    const float* sx = x + (size_t)n * (16u * 512u * 512u) + (size_t)refl(pr - 7) * 512;
    const int g0 = pc0 - 8;
    float v[8];
    if (g0 >= 0 && g0 <= 504) {
        const float4 a = *(const float4*)(sx + g0);
        const float4 b = *(const float4*)(sx + g0 + 4);
        v[0] = a.x; v[1] = a.y; v[2] = a.z; v[3] = a.w;
        v[4] = b.x; v[5] = b.y; v[6] = b.z; v[7] = b.w;
    } else {
        #pragma unroll
        for (int i = 0; i < 8; ++i) v[i] = sx[refl(g0 + i)];
    }
    uint4 q;
    q.x = (u32)f2bf(v[0]) | ((u32)f2bf(v[1]) << 16);
    q.y = (u32)f2bf(v[2]) | ((u32)f2bf(v[3]) << 16);
    q.z = (u32)f2bf(v[4]) | ((u32)f2bf(v[5]) << 16);
    q.w = (u32)f2bf(v[6]) | ((u32)f2bf(v[7]) << 16);
    *(uint4*)(P + (size_t)n * PIMG + (size_t)pr * PDIM + pc0) = q;
}

// ---------- pre-pass 2: pack weights into MFMA fragment layout ----------
// afragG[n][ks][lane] = 8 bf16 taps: oca=lane&15, g=lane>>4,
// kh = 2*ks + (g>>1), kw = 8*(g&1) + j  (zero-padded beyond 15x15)
__global__ __launch_bounds__(256) void packkern(const float* __restrict__ kern,
                                                uint4* __restrict__ afragG) {
    const int u = blockIdx.x * 256 + threadIdx.x;   // 16*8*64 = 8192 units
    const int n    = u >> 9;
    const int rem  = u & 511;
    const int ks   = rem >> 6;
    const int lane = rem & 63;
    const int oca = lane & 15, g = lane >> 4, g1 = g & 1, g2 = g >> 1;
    const float* kp = kern + ((size_t)n * 16 + oca) * 225;
    const int kh = 2 * ks + g2;
    u16 b[8];
    #pragma unroll
    for (int j = 0; j < 8; ++j) {
        const int kw = 8 * g1 + j;
        b[j] = f2bf((kh < 15 && kw < 15) ? kp[kh * 15 + kw] : 0.f);
    }
    uint4 q;
    q.x = (u32)b[0] | ((u32)b[1] << 16);
    q.y = (u32)b[2] | ((u32)b[3] << 16);
    q.z = (u32)b[4] | ((u32)b[5] << 16);
    q.w = (u32)b[6] | ((u32)b[7] << 16);
    afragG[u] = q;
}

// ---------- conv passes ----------
// Block (bx,by,bz): sample n=bz, rows h0=by*16..+15, cols c0=bx*32..+31, 16 oc.
// Wave w owns cols [c0+8w, c0+8w+8) via t=0..7; acc[8] f32x4.
// MODE 0: per-block max -> partial.  MODE 1: reduce partials, scale, store.
template <int MODE>
__global__ __launch_bounds__(256) void dynconv(const u16* __restrict__ P,
                                               const uint4* __restrict__ afragG,
                                               float* __restrict__ out,
                                               float* __restrict__ partial) {
    __shared__ __align__(16) u16 lds_in[IN_ROWS * IN_STRIDE];  // 3472 B
    __shared__ float wm[4];

    const int tid  = threadIdx.x;
    const int lane = tid & 63;
    const int wave = tid >> 6;
    const int c0 = blockIdx.x * 32;
    const int h0 = blockIdx.y * 16;
    const int n  = blockIdx.z;

    // ---- stage: branch-free b128 copy from padded image (single round) ----
    if (tid < IN_ROWS * 6) {
        const int rr  = tid / 6;
        const int cs8 = tid - rr * 6;
        const uint4 q = *(const uint4*)(P + (size_t)n * PIMG
                                        + (size_t)(h0 + rr) * PDIM + c0 + 8 * cs8);
        *(uint4*)&lds_in[rr * IN_STRIDE + 8 * cs8] = q;
    }

    // ---- A fragments: 8 coalesced b128 loads from packed table ----
    const int g  = lane >> 4;
    const int g1 = g & 1;
    const int g2 = g >> 1;
    bf16x8 afrag[8];
    {
        const uint4* ap = afragG + ((size_t)n << 9) + lane;   // [n][ks][lane]
        #pragma unroll
        for (int ks = 0; ks < 8; ++ks)
            afrag[ks] = __builtin_bit_cast(bf16x8, ap[ks << 6]);
    }

    // ---- MODE 1: per-sample max from this sample's 512 partials ----
    float scale = 0.f;
    if constexpr (MODE == 1) {
        const float* pp = partial + n * 512 + lane * 8;
        const float4 a = *(const float4*)pp;
        const float4 b = *(const float4*)(pp + 4);
        float pv = fmaxf(fmaxf(fmaxf(a.x, a.y), fmaxf(a.z, a.w)),
                         fmaxf(fmaxf(b.x, b.y), fmaxf(b.z, b.w)));
        #pragma unroll
        for (int off = 32; off > 0; off >>= 1) pv = fmaxf(pv, __shfl_xor(pv, off, 64));
        scale = 1.0f / pv;
    }

    __syncthreads();

    // ---- conv: 8 K-steps, double-buffered E reads (identical to r11) ----
    const int hh = lane & 15;
    const char* lbase = (const char*)lds_in
                        + (hh + g2) * (IN_STRIDE * 2) + 16 * (wave + g1);

    f32x4 acc[8];
    #pragma unroll
    for (int t = 0; t < 8; ++t) acc[t] = f32x4{0.f, 0.f, 0.f, 0.f};

    u32 Ea[8], Eb[8];
#define LDE(E, ks) do {                                                        \
        const uint4 _a = *(const uint4*)(lbase + (ks) * (2 * IN_STRIDE * 2));  \
        const uint4 _b = *(const uint4*)(lbase + (ks) * (2 * IN_STRIDE * 2) + 16); \
        E[0] = _a.x; E[1] = _a.y; E[2] = _a.z; E[3] = _a.w;                    \
        E[4] = _b.x; E[5] = _b.y; E[6] = _b.z; E[7] = _b.w; } while (0)
#define KSTEP(E, ks) do {                                                      \
        _Pragma("unroll")                                                      \
        for (int t = 0; t < 8; ++t) {                                          \
            const int s = t + 1, xb = s >> 1;                                  \
            u32 d0, d1, d2, d3;                                                \
            if (s & 1) {                                                       \
                d0 = __builtin_amdgcn_alignbit(E[xb + 1], E[xb], 16);          \
                d1 = __builtin_amdgcn_alignbit(E[xb + 2], E[xb + 1], 16);      \
                d2 = __builtin_amdgcn_alignbit(E[xb + 3], E[xb + 2], 16);      \
                d3 = __builtin_amdgcn_alignbit(E[xb + 4], E[xb + 3], 16);      \
            } else { d0 = E[xb]; d1 = E[xb + 1]; d2 = E[xb + 2]; d3 = E[xb + 3]; } \
            uint4 dv; dv.x = d0; dv.y = d1; dv.z = d2; dv.w = d3;              \
            acc[t] = __builtin_amdgcn_mfma_f32_16x16x32_bf16(                  \
                afrag[ks], __builtin_bit_cast(bf16x8, dv), acc[t], 0, 0, 0);   \
        } } while (0)

    LDE(Ea, 0);
    LDE(Eb, 1); KSTEP(Ea, 0);
    LDE(Ea, 2); KSTEP(Eb, 1);
    LDE(Eb, 3); KSTEP(Ea, 2);
    LDE(Ea, 4); KSTEP(Eb, 3);
    LDE(Eb, 5); KSTEP(Ea, 4);
    LDE(Ea, 6); KSTEP(Eb, 5);
    LDE(Eb, 7); KSTEP(Ea, 6);
    KSTEP(Eb, 7);
#undef LDE
#undef KSTEP

    if constexpr (MODE == 0) {
        float m = -3.4e38f;
        #pragma unroll
        for (int t = 0; t < 8; ++t)
            #pragma unroll
            for (int r = 0; r < 4; ++r) m = fmaxf(m, acc[t][r]);
        #pragma unroll
        for (int off = 32; off > 0; off >>= 1) m = fmaxf(m, __shfl_xor(m, off, 64));
        if (lane == 0) wm[wave] = m;
        __syncthreads();
        if (tid == 0)
            partial[n * 512 + blockIdx.y * 16 + blockIdx.x] =
                fmaxf(fmaxf(wm[0], wm[1]), fmaxf(wm[2], wm[3]));
    } else {
        // ---- coalesced epilogue: transpose through LDS (XOR-swizzled) ----
        // write: lane row oh_w = g*16+hh, cols 8w..8w+7 (chunk XOR'd by row)
        // read:  thread -> (oc2,h2) = tid>>2, ci = (tid&3)*8; 32B contiguous/thread
        __shared__ __align__(16) float lout[4 * 16 * 36];     // 9216 B
        const int oh_w  = g * 16 + hh;
        float* wp = &lout[oh_w * 36 + ((8 * wave) ^ (8 * (oh_w & 3)))];
        const int oh_r = tid >> 2;
        const int ci   = (tid & 3) * 8;
        const float* rp = &lout[oh_r * 36 + (ci ^ (8 * (oh_r & 3)))];
        const int oc2 = oh_r >> 4, h2 = oh_r & 15;

        #pragma unroll
        for (int r = 0; r < 4; ++r) {
            __syncthreads();   // protect previous r's reads
            f32x4 v0, v1;
            v0[0] = acc[0][r] * scale; v0[1] = acc[1][r] * scale;
            v0[2] = acc[2][r] * scale; v0[3] = acc[3][r] * scale;
            v1[0] = acc[4][r] * scale; v1[1] = acc[5][r] * scale;
            v1[2] = acc[6][r] * scale; v1[3] = acc[7][r] * scale;
            *(f32x4*)wp       = v0;
            *(f32x4*)(wp + 4) = v1;
            __syncthreads();
            const f32x4 s0 = *(const f32x4*)rp;
            const f32x4 s1 = *(const f32x4*)(rp + 4);
            float* orow = out + (((size_t)((4 * oc2 + r) * 16 + n)) * 512
                                 + (size_t)(h0 + h2)) * 512 + c0 + ci;
            *(f32x4*)orow       = s0;
            *(f32x4*)(orow + 4) = s1;
        }
    }
}

extern "C" void kernel_launch(void* const* d_in, const int* in_sizes, int n_in,
                              void* d_out, int out_size, void* d_ws, size_t ws_size,
                              hipStream_t stream) {
    (void)in_sizes; (void)n_in; (void)out_size; (void)ws_size;
    const float* x  = (const float*)d_in[0];
    const float* k  = (const float*)d_in[1];
    float* out      = (float*)d_out;
    u16* P          = (u16*)d_ws;                               // 8.92 MB padded bf16
    uint4* afragG   = (uint4*)((char*)d_ws + (10u << 20));      // 128 KB packed weights
    float* partial  = (float*)((char*)d_ws + (12u << 20));      // 32 KB partial maxima

    cvtpad<<<dim3(16 * PDIM * 66 / 256), dim3(256), 0, stream>>>(x, P);
    packkern<<<dim3(32), dim3(256), 0, stream>>>(k, afragG);
    dim3 grid(16, 32, 16);   // 32-col x 16-row x sample = 8192 blocks
    dim3 block(256);
    dynconv<0><<<grid, block, 0, stream>>>(P, afragG, out, partial);  // max pass
    dynconv<1><<<grid, block, 0, stream>>>(P, afragG, out, partial);  // scale+store
}